// Round 7
// baseline (741.934 us; speedup 1.0000x reference)
//
#include <hip/hip_runtime.h>
#include <cstddef>

// Problem constants (from reference): T=1024, B=64, DIM=512, N=64
#define T_STEPS 1024
#define BATCH   64
#define DIMK    512
#define NDIM    64
#define PROJW   256   // 4*N
#define STEPSTRIDE (BATCH * PROJW)

typedef __attribute__((ext_vector_type(8))) short short8;
typedef __attribute__((ext_vector_type(4))) float f32x4;
typedef __attribute__((ext_vector_type(2))) unsigned int uint2v;

// fast sigmoid: v_exp + v_rcp (1-2 ulp), avoids the IEEE div sequence.
__device__ __forceinline__ float sigmoidf_(float x) {
    return __builtin_amdgcn_rcpf(1.0f + __expf(-x));
}

// DPP row-rotate move: dst lane i <- src lane (i+N) mod 16 (within each 16-lane row)
template<int CTRL>
__device__ __forceinline__ float dpp_mov(float x) {
    return __int_as_float(__builtin_amdgcn_update_dpp(
        0, __float_as_int(x), CTRL, 0xF, 0xF, true));
}
// 32-lane allreduce: 4 DPP rotate-adds within each 16-row, then cross-16 via
// v_permlane16_swap (VALU pipe, ~5cyc) instead of ds_bpermute (~50cyc LDS pipe):
// with both operands = x, the returned pair is (even-row dup, odd-row dup);
// their sum gives every lane its 32-group total.
__device__ __forceinline__ float redrow32(float x) {
    x += dpp_mov<0x128>(x);
    x += dpp_mov<0x124>(x);
    x += dpp_mov<0x122>(x);
    x += dpp_mov<0x121>(x);
    uint2v r = __builtin_amdgcn_permlane16_swap(__float_as_uint(x), __float_as_uint(x),
                                                false, false);
    return __uint_as_float(r.x) + __uint_as_float(r.y);
}

// round-to-nearest-even f32 -> bf16 bits
__device__ __forceinline__ unsigned short f2bf(float f) {
    unsigned u = __float_as_uint(f);
    return (unsigned short)((u + 0x7FFFu + ((u >> 16) & 1u)) >> 16);
}

// ---------------------------------------------------------------------------
// Kernel 0: split f32 -> (bf16 hi, bf16 lo) with lo = bf16(x - float(hi)).
// ---------------------------------------------------------------------------
__global__ __launch_bounds__(256) void cvt_split(const float* __restrict__ src,
                                                 unsigned short* __restrict__ hi,
                                                 unsigned short* __restrict__ lo,
                                                 int n4) {
    for (int idx = blockIdx.x * 256 + threadIdx.x; idx < n4; idx += gridDim.x * 256) {
        float4 v = ((const float4*)src)[idx];
        ushort4 h, l;
#define CV(c, fld) { unsigned short hb = f2bf(v.c); h.fld = hb; \
                     float hf = __uint_as_float(((unsigned)hb) << 16); \
                     l.fld = f2bf(v.c - hf); }
        CV(x, x) CV(y, y) CV(z, z) CV(w, w)
#undef CV
        ((ushort4*)hi)[idx] = h;
        ((ushort4*)lo)[idx] = l;
    }
}

// ---------------------------------------------------------------------------
// Kernel 1 (MFMA): C[M][256] = Xhi*Whi^T + Xhi*Wlo^T + Xlo*Whi^T  (bf16 MFMA,
// f32 accumulate; dropped lo*lo term ~2^-16 relative). K' = 3 sections x 512.
// 128x128 tile, 4 waves (2x2), wave tile 64x64 = 4x4 fragments of 16x16x32.
// LDS rows padded 32->40 bf16: frag ds_read_b128 spreads 8 rows over all 32
// banks (2 lanes/bank = free); staging writes same pattern.
// Operand maps (m89/m92-verified): A lane l -> row l&15, k (l>>4)*8+j;
// B same with n=l&15; D -> col=l&15, row=(l>>4)*4+reg.
// ---------------------------------------------------------------------------
__global__ __launch_bounds__(256) void proj_gemm_mfma(
        const unsigned short* __restrict__ Xhi, const unsigned short* __restrict__ Xlo,
        const unsigned short* __restrict__ Whi, const unsigned short* __restrict__ Wlo,
        float* __restrict__ C) {
    __shared__ unsigned short sA[128][40];
    __shared__ unsigned short sB[128][40];
    const int tid  = threadIdx.x;
    const int row0 = blockIdx.x * 128;      // 512 row tiles
    const int col0 = blockIdx.y * 128;      // 2 col tiles
    const int w    = tid >> 6;              // wave 0..3
    const int l    = tid & 63;
    const int wr   = w >> 1, wc = w & 1;    // 2x2 wave grid
    const int l15  = l & 15, lh = l >> 4;
    const int r0   = tid >> 2;              // staging row 0..63
    const int p0   = (tid & 3) << 3;        // staging k-offset (bf16): 0,8,16,24

    f32x4 acc[4][4] = {};
    uint4 ra0, ra1, rb0, rb1;

    // prologue load (it=0: section 0, kin=0)
    ra0 = *(const uint4*)(Xhi + (size_t)(row0 + r0)      * DIMK + p0);
    ra1 = *(const uint4*)(Xhi + (size_t)(row0 + 64 + r0) * DIMK + p0);
    rb0 = *(const uint4*)(Whi + (size_t)(col0 + r0)      * DIMK + p0);
    rb1 = *(const uint4*)(Whi + (size_t)(col0 + 64 + r0) * DIMK + p0);

    for (int it = 0; it < 48; ++it) {
        __syncthreads();   // previous iteration's readers done
        *(uint4*)&sA[r0][p0]      = ra0;
        *(uint4*)&sA[64 + r0][p0] = ra1;
        *(uint4*)&sB[r0][p0]      = rb0;
        *(uint4*)&sB[64 + r0][p0] = rb1;
        __syncthreads();
        if (it + 1 < 48) {
            const int s   = (it + 1) >> 4;            // section 0,1,2
            const int kin = ((it + 1) & 15) << 5;     // k within section
            const unsigned short* Ap = (s == 2) ? Xlo : Xhi;
            const unsigned short* Bp = (s == 1) ? Wlo : Whi;
            ra0 = *(const uint4*)(Ap + (size_t)(row0 + r0)      * DIMK + kin + p0);
            ra1 = *(const uint4*)(Ap + (size_t)(row0 + 64 + r0) * DIMK + kin + p0);
            rb0 = *(const uint4*)(Bp + (size_t)(col0 + r0)      * DIMK + kin + p0);
            rb1 = *(const uint4*)(Bp + (size_t)(col0 + 64 + r0) * DIMK + kin + p0);
        }
        short8 af[4], bf_[4];
        #pragma unroll
        for (int mi = 0; mi < 4; ++mi)
            af[mi] = *(const short8*)&sA[wr * 64 + mi * 16 + l15][lh * 8];
        #pragma unroll
        for (int ni = 0; ni < 4; ++ni)
            bf_[ni] = *(const short8*)&sB[wc * 64 + ni * 16 + l15][lh * 8];
        #pragma unroll
        for (int mi = 0; mi < 4; ++mi)
            #pragma unroll
            for (int ni = 0; ni < 4; ++ni)
                acc[mi][ni] = __builtin_amdgcn_mfma_f32_16x16x32_bf16(
                    af[mi], bf_[ni], acc[mi][ni], 0, 0, 0);
    }

    #pragma unroll
    for (int mi = 0; mi < 4; ++mi)
        #pragma unroll
        for (int ni = 0; ni < 4; ++ni)
            #pragma unroll
            for (int r = 0; r < 4; ++r) {
                const int row = row0 + wr * 64 + mi * 16 + lh * 4 + r;
                const int col = col0 + wc * 64 + ni * 16 + l15;
                C[(size_t)row * PROJW + col] = acc[mi][ni][r];
            }
}

// ---------------------------------------------------------------------------
// Kernel 1 fallback (f32 vector GEMM, round-4 version) — used if ws too small.
// ---------------------------------------------------------------------------
__global__ __launch_bounds__(256) void proj_gemm(const float* __restrict__ X,
                                                 const float* __restrict__ W,
                                                 float* __restrict__ C) {
    __shared__ float As[16][132];
    __shared__ float Bs[16][132];
    const int tid  = threadIdx.x;
    const int row0 = blockIdx.x * 128;
    const int col0 = blockIdx.y * 128;
    const int tx4  = (tid & 15) << 2;
    const int ty4  = (tid >> 4) << 2;
    const int lm   = tid >> 2;
    const int lk   = (tid & 3) << 2;

    const float* Arow0 = X + (size_t)(row0 + lm)      * DIMK + lk;
    const float* Arow1 = X + (size_t)(row0 + lm + 64) * DIMK + lk;
    const float* Brow0 = W + (size_t)(col0 + lm)      * DIMK + lk;
    const float* Brow1 = W + (size_t)(col0 + lm + 64) * DIMK + lk;

    float acc[8][8] = {};
    float4 pa0 = *(const float4*)(Arow0);
    float4 pa1 = *(const float4*)(Arow1);
    float4 pb0 = *(const float4*)(Brow0);
    float4 pb1 = *(const float4*)(Brow1);

    for (int tile = 0; tile < DIMK / 16; ++tile) {
        __syncthreads();
        As[lk+0][lm]    = pa0.x; As[lk+1][lm]    = pa0.y; As[lk+2][lm]    = pa0.z; As[lk+3][lm]    = pa0.w;
        As[lk+0][lm+64] = pa1.x; As[lk+1][lm+64] = pa1.y; As[lk+2][lm+64] = pa1.z; As[lk+3][lm+64] = pa1.w;
        Bs[lk+0][lm]    = pb0.x; Bs[lk+1][lm]    = pb0.y; Bs[lk+2][lm]    = pb0.z; Bs[lk+3][lm]    = pb0.w;
        Bs[lk+0][lm+64] = pb1.x; Bs[lk+1][lm+64] = pb1.y; Bs[lk+2][lm+64] = pb1.z; Bs[lk+3][lm+64] = pb1.w;
        __syncthreads();
        if (tile + 1 < DIMK / 16) {
            const int kb = (tile + 1) * 16;
            pa0 = *(const float4*)(Arow0 + kb);
            pa1 = *(const float4*)(Arow1 + kb);
            pb0 = *(const float4*)(Brow0 + kb);
            pb1 = *(const float4*)(Brow1 + kb);
        }
        #pragma unroll 8
        for (int k = 0; k < 16; ++k) {
            const float4 a0v = *(const float4*)&As[k][ty4];
            const float4 a1v = *(const float4*)&As[k][64 + ty4];
            const float4 b0v = *(const float4*)&Bs[k][tx4];
            const float4 b1v = *(const float4*)&Bs[k][64 + tx4];
            const float a[8]  = {a0v.x, a0v.y, a0v.z, a0v.w, a1v.x, a1v.y, a1v.z, a1v.w};
            const float bb[8] = {b0v.x, b0v.y, b0v.z, b0v.w, b1v.x, b1v.y, b1v.z, b1v.w};
            #pragma unroll
            for (int i2 = 0; i2 < 8; ++i2)
                #pragma unroll
                for (int j2 = 0; j2 < 8; ++j2)
                    acc[i2][j2] = fmaf(a[i2], bb[j2], acc[i2][j2]);
        }
    }
    #pragma unroll
    for (int h = 0; h < 2; ++h)
        #pragma unroll
        for (int r = 0; r < 4; ++r) {
            const size_t R = (size_t)(row0 + h * 64 + ty4 + r) * PROJW + col0;
            float4 o0 = {acc[h*4+r][0], acc[h*4+r][1], acc[h*4+r][2], acc[h*4+r][3]};
            float4 o1 = {acc[h*4+r][4], acc[h*4+r][5], acc[h*4+r][6], acc[h*4+r][7]};
            *(float4*)&C[R + tx4]      = o0;
            *(float4*)&C[R + 64 + tx4] = o1;
        }
}

// ---------------------------------------------------------------------------
// Kernel 1.5: normalize k (cols 0..63) and m (cols 192..255) of proj in place.
// ---------------------------------------------------------------------------
__global__ __launch_bounds__(256) void normalize_km(float* __restrict__ proj) {
    const int p    = blockIdx.x * 4 + (threadIdx.x >> 6);
    const int lane = threadIdx.x & 63;
    float* base = proj + (size_t)p * PROJW;
    const float k = base[lane];
    const float m = base[192 + lane];
    float sk = k * k, sm = m * m;
    #pragma unroll
    for (int d = 1; d < 64; d <<= 1) {
        sk += __shfl_xor(sk, d);
        sm += __shfl_xor(sm, d);
    }
    base[lane]       = k / (sqrtf(sk) + 1e-6f);
    base[192 + lane] = m / (sqrtf(sm) + 1e-6f);
}

// ---------------------------------------------------------------------------
// Kernel 2: sequential recurrence — barrier-free, LDS-free, 2 waves/SIMD,
// reductions fully on the VALU pipe (DPP + permlane16_swap, zero ds ops).
// 512 blocks x 256 threads; 32 lanes/row, 2 cols/lane.
// ---------------------------------------------------------------------------
__global__ __launch_bounds__(256) void recur_kernel(const float* __restrict__ proj,
                                                    const float* __restrict__ S0,
                                                    const float* __restrict__ M0,
                                                    const float* __restrict__ BSmat,
                                                    const float* __restrict__ BMmat,
                                                    float* __restrict__ outp,
                                                    float* __restrict__ Sout,
                                                    float* __restrict__ Mout) {
    const int tid = threadIdx.x;
    const int b   = blockIdx.x & 63;
    const int oct = blockIdx.x >> 6;
    const int lr  = tid >> 5;
    const int i   = (oct << 3) + lr;
    const int l32 = tid & 31;
    const int j0  = l32 << 1;

    float S[2], Mr[2], BSr[2], BMr[2];
    const size_t smoff = ((size_t)b * NDIM + i) * NDIM + j0;
    { float2 t2 = *(const float2*)&S0[smoff];                    S[0]=t2.x;  S[1]=t2.y;  }
    { float2 t2 = *(const float2*)&M0[smoff];                    Mr[0]=t2.x; Mr[1]=t2.y; }
    { float2 t2 = *(const float2*)&BSmat[(size_t)i * NDIM + j0]; BSr[0]=t2.x;BSr[1]=t2.y;}
    { float2 t2 = *(const float2*)&BMmat[(size_t)i * NDIM + j0]; BMr[0]=t2.x;BMr[1]=t2.y;}

    const float* pb = proj + (size_t)b * PROJW;

    auto step = [&](int t, float2 kn2, float2 q2, float2 mn2, float v_i) {
        float Mk = Mr[0] * kn2.x; Mk = fmaf(Mr[1], kn2.y, Mk);
        float Sk = S[0]  * kn2.x; Sk = fmaf(S[1],  kn2.y, Sk);
        float Mm = Mr[0] * mn2.x; Mm = fmaf(Mr[1], mn2.y, Mm);
        Mk = redrow32(Mk); Sk = redrow32(Sk); Mm = redrow32(Mm);
        const float sd = v_i - Sk;
        {
            const float g0 = sigmoidf_(fmaf(Mk, kn2.x, Mr[0]) + BSr[0]);
            const float g1 = sigmoidf_(fmaf(Mk, kn2.y, Mr[1]) + BSr[1]);
            S[0] = fmaf(g0, S[0], sd * kn2.x);
            S[1] = fmaf(g1, S[1], sd * kn2.y);
        }
        float Sm = S[0] * mn2.x; Sm = fmaf(S[1], mn2.y, Sm);
        float Sq = S[0] * q2.x;  Sq = fmaf(S[1], q2.y,  Sq);
        Sm = redrow32(Sm); Sq = redrow32(Sq);
        const float md = sd - Mm;
        {
            const float g0 = sigmoidf_(fmaf(Sm, mn2.x, S[0]) + BMr[0]);
            const float g1 = sigmoidf_(fmaf(Sm, mn2.y, S[1]) + BMr[1]);
            Mr[0] = fmaf(g0, Mr[0], md * mn2.x);
            Mr[1] = fmaf(g1, Mr[1], md * mn2.y);
        }
        if (l32 == 0) {
            outp[(size_t)t * (BATCH * NDIM) + b * NDIM + i] = Sq * Sq * sigmoidf_(Sq);
        }
    };

#define DECL_SET(s) float2 kn##s, q##s, mn##s; float vi##s;
#define LOAD_SET(s, tt) { \
        const float* r_ = pb + (size_t)(tt) * STEPSTRIDE; \
        kn##s = *(const float2*)(r_ + j0); \
        q##s  = *(const float2*)(r_ + 128 + j0); \
        mn##s = *(const float2*)(r_ + 192 + j0); \
        vi##s = r_[64 + i]; }

    DECL_SET(0) DECL_SET(1) DECL_SET(2) DECL_SET(3)
    LOAD_SET(0, 0) LOAD_SET(1, 1) LOAD_SET(2, 2) LOAD_SET(3, 3)

    // main loop: t = 0..1016; prefetch indices t+4..t+7 <= 1023 -> no clamp.
    for (int t = 0; t < T_STEPS - 4; t += 4) {
        step(t + 0, kn0, q0, mn0, vi0); LOAD_SET(0, t + 4);
        step(t + 1, kn1, q1, mn1, vi1); LOAD_SET(1, t + 5);
        step(t + 2, kn2, q2, mn2, vi2); LOAD_SET(2, t + 6);
        step(t + 3, kn3, q3, mn3, vi3); LOAD_SET(3, t + 7);
    }
    step(T_STEPS - 4, kn0, q0, mn0, vi0);
    step(T_STEPS - 3, kn1, q1, mn1, vi1);
    step(T_STEPS - 2, kn2, q2, mn2, vi2);
    step(T_STEPS - 1, kn3, q3, mn3, vi3);
#undef DECL_SET
#undef LOAD_SET

    { float2 o = {S[0], S[1]};   *(float2*)&Sout[smoff] = o; }
    { float2 o = {Mr[0], Mr[1]}; *(float2*)&Mout[smoff] = o; }
}

// ---------------------------------------------------------------------------
extern "C" void kernel_launch(void* const* d_in, const int* in_sizes, int n_in,
                              void* d_out, int out_size, void* d_ws, size_t ws_size,
                              hipStream_t stream) {
    const float* x   = (const float*)d_in[0];   // (T,B,DIM) f32
    const float* S0  = (const float*)d_in[1];   // (B,N,N)
    const float* M0  = (const float*)d_in[2];   // (B,N,N)
    const float* W   = (const float*)d_in[3];   // (4N,DIM)
    const float* BS  = (const float*)d_in[4];   // (N,N)
    const float* BMb = (const float*)d_in[5];   // (N,N)
    float* out = (float*)d_out;

    const size_t XN = (size_t)T_STEPS * BATCH * DIMK;     // 33.55M
    const size_t WN = (size_t)PROJW * DIMK;               // 131072
    const size_t PROJB = (size_t)T_STEPS * BATCH * PROJW * sizeof(float);  // 64 MB
    const size_t need  = PROJB + 2 * XN * 2 + 2 * WN * 2; // ~202 MB

    float* proj = (float*)d_ws;

    if (ws_size >= need) {
        unsigned short* Xhi = (unsigned short*)((char*)d_ws + PROJB);
        unsigned short* Xlo = Xhi + XN;
        unsigned short* Whi = Xlo + XN;
        unsigned short* Wlo = Whi + WN;
        cvt_split<<<dim3(2048), dim3(256), 0, stream>>>(x, Xhi, Xlo, (int)(XN / 4));
        cvt_split<<<dim3(128),  dim3(256), 0, stream>>>(W, Whi, Wlo, (int)(WN / 4));
        proj_gemm_mfma<<<dim3(512, 2), dim3(256), 0, stream>>>(Xhi, Xlo, Whi, Wlo, proj);
    } else {
        proj_gemm<<<dim3(512, 2), dim3(256), 0, stream>>>(x, W, proj);
    }

    normalize_km<<<dim3(T_STEPS * BATCH / 4), dim3(256), 0, stream>>>(proj);

    float* Sout = out + (size_t)T_STEPS * BATCH * NDIM;
    float* Mout = Sout + (size_t)BATCH * NDIM * NDIM;
    recur_kernel<<<dim3(BATCH * 8), dim3(256), 0, stream>>>(proj, S0, M0, BS, BMb,
                                                            out, Sout, Mout);
}